// Round 7
// baseline (155.744 us; speedup 1.0000x reference)
//
#include <hip/hip_runtime.h>
#include <hip/hip_bf16.h>

#define DM 1024
#define NH 16
#define DK 64
#define TT 2048
#define NBATCH 4
#define BT 8192   // NBATCH*TT

typedef __attribute__((ext_vector_type(8))) short short8;
typedef __attribute__((ext_vector_type(4))) float f32x4;
typedef unsigned short u16;

#define MFMA(a,b,c) __builtin_amdgcn_mfma_f32_16x16x32_bf16((a),(b),(c),0,0,0)

// 1/sqrt(64) * log2(e): folded into Q so attn softmax can use exp2 directly
#define QSCALE 0.18033688011112684f

// raw v_exp_f32 (flush-denorm fine for softmax), skips OCML fixup code
#define EXP2(x) __builtin_amdgcn_exp2f(x)

__device__ __forceinline__ u16 f2bf(float f){
  union { float f; unsigned u; } v; v.f = f;
  return (u16)((v.u + 0x7fffu + ((v.u >> 16) & 1u)) >> 16);
}

__device__ __forceinline__ unsigned cvtpk(float lo, float hi){
  unsigned r;
  asm("v_cvt_pk_bf16_f32 %0, %1, %2" : "=v"(r) : "v"(lo), "v"(hi));
  return r;
}

// async global->LDS DMA, 16B/lane. LDS dest must be wave-uniform base (+lane*16).
__device__ __forceinline__ void gload16(const void* g, void* l){
  __builtin_amdgcn_global_load_lds((__attribute__((address_space(1))) void*)(g),
                                   (__attribute__((address_space(3))) void*)(l), 16, 0, 0);
}

// cross-lane reduce over the 4 16-lane groups (lane ^16, ^32): pure-VALU permlanes
__device__ __forceinline__ float plmax(float x){
#if __has_builtin(__builtin_amdgcn_permlane16_swap) && __has_builtin(__builtin_amdgcn_permlane32_swap)
  auto r = __builtin_amdgcn_permlane16_swap(__float_as_uint(x), __float_as_uint(x), false, false);
  x = fmaxf(__uint_as_float(r[0]), __uint_as_float(r[1]));
  auto r2 = __builtin_amdgcn_permlane32_swap(__float_as_uint(x), __float_as_uint(x), false, false);
  x = fmaxf(__uint_as_float(r2[0]), __uint_as_float(r2[1]));
#else
  x = fmaxf(x, __shfl_xor(x, 16, 64));
  x = fmaxf(x, __shfl_xor(x, 32, 64));
#endif
  return x;
}

__device__ __forceinline__ float plsum(float x){
#if __has_builtin(__builtin_amdgcn_permlane16_swap) && __has_builtin(__builtin_amdgcn_permlane32_swap)
  auto r = __builtin_amdgcn_permlane16_swap(__float_as_uint(x), __float_as_uint(x), false, false);
  x = __uint_as_float(r[0]) + __uint_as_float(r[1]);
  auto r2 = __builtin_amdgcn_permlane32_swap(__float_as_uint(x), __float_as_uint(x), false, false);
  x = __uint_as_float(r2[0]) + __uint_as_float(r2[1]);
#else
  x = x + __shfl_xor(x, 16, 64);
  x = x + __shfl_xor(x, 32, 64);
#endif
  return x;
}

// ---------------- x fp32 -> bf16 ----------------
__global__ __launch_bounds__(256) void cvt_x(const float* __restrict__ x, u16* __restrict__ xb){
  int i = (blockIdx.x * 256 + threadIdx.x) * 4;
  float4 v = *(const float4*)(x + i);
  u16 o0 = f2bf(v.x), o1 = f2bf(v.y), o2 = f2bf(v.z), o3 = f2bf(v.w);
  ushort4 o; o.x=o0; o.y=o1; o.z=o2; o.w=o3;
  *(ushort4*)(xb + i) = o;
}

// ---------------- W (K,N) fp32 -> wt (N,K) bf16, all 3 mats in one launch ----------------
__global__ __launch_bounds__(256) void twp(
    const float* __restrict__ Wq, const float* __restrict__ Wk, const float* __restrict__ Wv,
    u16* __restrict__ wtq, u16* __restrict__ wtk, u16* __restrict__ wtv){
  const float* W = (blockIdx.z == 0) ? Wq : (blockIdx.z == 1) ? Wk : Wv;
  u16* wt = (blockIdx.z == 0) ? wtq : (blockIdx.z == 1) ? wtk : wtv;
  __shared__ float tile[32][33];
  int k0 = blockIdx.x * 32, n0 = blockIdx.y * 32;
  int tx = threadIdx.x & 31, ty = threadIdx.x >> 5;
  #pragma unroll
  for(int r = ty; r < 32; r += 8)
    tile[r][tx] = W[(size_t)(k0 + r) * DM + n0 + tx];
  __syncthreads();
  #pragma unroll
  for(int r = ty; r < 32; r += 8)
    wt[(size_t)(n0 + r) * DM + k0 + tx] = f2bf(tile[tx][r]);
}

// ---------------- QKV projection GEMM: 256x256 8-phase (m201-template port) ----------------
// BM=BN=256, BK=64, 8 waves (2M x 4N); per-wave C = 128x64 = 8x4 16x16 frags.
// LDS = 2 bufs x (A 32KB + B 32KB) = 128KB dynamic. Counted vmcnt(8), never 0 in
// the loop: boundary = {burst-stage next tile into just-freed buf; vmcnt(8) waits
// the tile about to be read; barrier}. 4 phases per K-tile, zigzag quadrant order
// (rh,ch) = (0,0)->(1,0)->(1,1)->(0,1) reuses af/bf frags to cut LDS reads.
// Each phase: ds_read -> s_barrier -> lgkmcnt(0)+sched_barrier (rule 18) ->
// setprio(1) 16 MFMA setprio(0) -> s_barrier.  Swizzle: linear LDS dest +
// inverse-swizzled global source + XOR on read (rule 21, verified pattern).
// Grid 384: XCD k owns M-tiles [4k,4k+4) (2MB x-stripe = its L2).
#define STAGE(TT_, LB_) { \
  int kk_ = (TT_) * 64; \
  _Pragma("unroll") \
  for(int p_ = 0; p_ < 4; p_++){ \
    int base_ = p_ * 512 + (tid & 448); \
    int ci_ = base_ + lane; \
    int row_ = ci_ >> 3, chs_ = (ci_ & 7) ^ (row_ & 7); \
    gload16(xb + (size_t)(m0 + row_) * 1024 + kk_ + chs_ * 8, (LB_) + base_ * 16); \
  } \
  _Pragma("unroll") \
  for(int p_ = 0; p_ < 4; p_++){ \
    int base_ = p_ * 512 + (tid & 448); \
    int ci_ = base_ + lane; \
    int row_ = ci_ >> 3, chs_ = (ci_ & 7) ^ (row_ & 7); \
    gload16(wt + (size_t)(n0 + row_) * 1024 + kk_ + chs_ * 8, (LB_) + 32768 + base_ * 16); \
  } }

#define PHASE(LB_, RH, CH, RA, RB) { \
  const char* A_ = (LB_); const char* B_ = (LB_) + 32768; \
  if(RA){ \
    _Pragma("unroll") \
    for(int i2 = 0; i2 < 4; i2++){ \
      int ra_ = wm + ((RH)*4 + i2) * 16 + ln; int swa_ = (ra_ & 7) << 4; \
      af[i2][0] = *(const short8*)(A_ + ra_ * 128 + ((g * 16) ^ swa_)); \
      af[i2][1] = *(const short8*)(A_ + ra_ * 128 + ((64 + g * 16) ^ swa_)); \
    } } \
  if(RB){ \
    _Pragma("unroll") \
    for(int j2 = 0; j2 < 2; j2++){ \
      int rb_ = wn + ((CH)*2 + j2) * 16 + ln; int swb_ = (rb_ & 7) << 4; \
      bf[j2][0] = *(const short8*)(B_ + rb_ * 128 + ((g * 16) ^ swb_)); \
      bf[j2][1] = *(const short8*)(B_ + rb_ * 128 + ((64 + g * 16) ^ swb_)); \
    } } \
  __builtin_amdgcn_s_barrier(); \
  asm volatile("s_waitcnt lgkmcnt(0)" ::: "memory"); \
  __builtin_amdgcn_sched_barrier(0); \
  __builtin_amdgcn_s_setprio(1); \
  _Pragma("unroll") \
  for(int ks2 = 0; ks2 < 2; ks2++) \
    _Pragma("unroll") \
    for(int i2 = 0; i2 < 4; i2++) \
      _Pragma("unroll") \
      for(int j2 = 0; j2 < 2; j2++) \
        acc[(RH)*4+i2][(CH)*2+j2] = MFMA(af[i2][ks2], bf[j2][ks2], acc[(RH)*4+i2][(CH)*2+j2]); \
  __builtin_amdgcn_s_setprio(0); \
  __builtin_amdgcn_s_barrier(); }

__global__ __launch_bounds__(512, 1) void qkv8(
    const u16* __restrict__ xb,
    const u16* __restrict__ wtq, const u16* __restrict__ wtk, const u16* __restrict__ wtv,
    const float* __restrict__ bq, const float* __restrict__ bk, const float* __restrict__ bv,
    u16* __restrict__ qws, u16* __restrict__ kws, u16* __restrict__ vtws){
  extern __shared__ char smem[];
  char* b0 = smem;
  char* b1 = smem + 65536;

  const int id = blockIdx.x;                 // 0..383
  const int xcd = id & 7, local = id >> 3;   // local 0..47
  const int mt = xcd * 4 + (local & 3);      // M-tile 0..31
  const int panel = local >> 2;              // 0..11
  const int m0 = mt * 256;
  const int mat = panel >> 2;                // 0..2
  const int n0 = (panel & 3) * 256;
  const u16* wt = (mat == 0) ? wtq : (mat == 1) ? wtk : wtv;
  const float* bias = (mat == 0) ? bq : (mat == 1) ? bk : bv;

  const int tid = threadIdx.x, lane = tid & 63, w = tid >> 6;   // w 0..7
  const int g = lane >> 4, ln = lane & 15;
  const int wm = (w >> 2) * 128;             // 2 M-wave-groups
  const int wn = (w & 3) * 64;               // 4 N-wave-groups

  f32x4 acc[8][4] = {};
  short8 af[4][2], bf[2][2];

  STAGE(0, b0);                              // tile 0 -> buf0 (8 loads/thread)

  #pragma unroll 1
  for(int it = 0; it < 8; it++){
    const int t = 2 * it;
    // boundary A: buf1 free (prev iter's reads drained) -> stage tile t+1
    STAGE((t + 1) & 15, b1);
    asm volatile("s_waitcnt vmcnt(8)" ::: "memory");   // tile t landed (per-wave)
    __builtin_amdgcn_s_barrier();                      // all waves confirmed
    PHASE(b0, 0, 0, 1, 1)
    PHASE(b0, 1, 0, 1, 0)
    PHASE(b0, 1, 1, 0, 1)
    PHASE(b0, 0, 1, 1, 0)
    // boundary B: buf0 free -> stage tile t+2 ((&15): last iter restages tile 0, harmless)
    STAGE((t + 2) & 15, b0);
    asm volatile("s_waitcnt vmcnt(8)" ::: "memory");   // tile t+1 landed
    __builtin_amdgcn_s_barrier();
    PHASE(b1, 0, 0, 1, 1)
    PHASE(b1, 1, 0, 1, 0)
    PHASE(b1, 1, 1, 0, 1)
    PHASE(b1, 0, 1, 1, 0)
  }
  asm volatile("s_waitcnt vmcnt(0)" ::: "memory");     // drain tail stages before exit

  const float scl = (mat == 0) ? QSCALE : 1.0f;
  #pragma unroll
  for(int j = 0; j < 4; j++){
    int n = n0 + wn + j * 16 + ln;
    float bv_ = bias[n];
    int h = n >> 6, d = n & 63;
    #pragma unroll
    for(int i = 0; i < 8; i++){
      int mb = m0 + wm + i * 16 + g * 4;     // 4-aligned, quad stays in-batch
      int b = mb >> 11, t = mb & 2047;
      int bh = b * NH + h;
      if(mat == 2){
        // V^T store, KEY-PERMUTED within each 32-key group for attn's PV b128 reads
        ushort4 o4;
        o4.x = f2bf(acc[i][j][0] + bv_);
        o4.y = f2bf(acc[i][j][1] + bv_);
        o4.z = f2bf(acc[i][j][2] + bv_);
        o4.w = f2bf(acc[i][j][3] + bv_);
        int tp = (t & ~31) | (((t >> 2) & 3) << 3) | (((t >> 4) & 1) << 2);
        *(ushort4*)(vtws + ((size_t)bh * DK + d) * TT + tp) = o4;
      } else {
        u16* dst = (mat == 0) ? qws : kws;
        #pragma unroll
        for(int r = 0; r < 4; r++){
          u16 o = f2bf((acc[i][j][r] + bv_) * scl);
          dst[((size_t)bh * TT + t + r) * DK + d] = o;
        }
      }
    }
  }
}

// ---------------- flash attention (swapped QK^T, in-register softmax) ----------------
// 8-wave blocks, 128 q-rows per q-tile; grid 512, bijective XCD swizzle; pairs
// (x, 15-x) -> exactly 34 k-iterations per block. Lower 4 waves skip their fully
// masked final k-tile. Counted per-iter DMA prefetch drained at next barrier.
__global__ __launch_bounds__(512) void attn(
    const u16* __restrict__ qws, const u16* __restrict__ kws, const u16* __restrict__ vtws,
    float* __restrict__ out){
  __shared__ u16 kt[2][64 * 64];    // [buf][key][d]  swizzled
  __shared__ u16 vt[2][64 * 64];    // [buf][d][key-permuted]  swizzled

  const int id = blockIdx.x;
  const int swz = (id & 7) * 64 + (id >> 3);   // bijective (512 % 8 == 0)
  const int qx = swz & 7;                      // pair index 0..7
  const int bh = swz >> 3;

  const int tid = threadIdx.x, lane = tid & 63, w = tid >> 6;   // w 0..7
  const int g = lane >> 4, ln = lane & 15;
  const int b = bh >> 4, h = bh & 15;
  const u16* kbase = kws + (size_t)bh * TT * DK;
  const u16* vbase = vtws + (size_t)bh * DK * TT;
  const int sbase = tid & 448;      // wave-uniform 16B-chunk base (HW adds lane*16)
  const int srow = tid >> 3;        // staging row 0..63
  const int schs = (tid & 7) ^ (srow & 7);     // inverse swizzle on the SOURCE

  #pragma unroll 1
  for(int qi = 0; qi < 2; qi++){
    const int qt = qi ? (15 - qx) : qx;        // 128-row q-tile 0..15
    const int q = qt * 128 + w * 16 + ln;      // this lane's q row

    // Q fragment (B-operand; pre-scaled by QSCALE): k-slots d = g*8+j (+32)
    short8 qf[2];
    {
      const u16* gq = qws + ((size_t)bh * TT + q) * DK + g * 8;
      qf[0] = *(const short8*)gq;
      qf[1] = *(const short8*)(gq + 32);
    }

    f32x4 o[4] = {};                 // O^T frags: o[i][r] = O^T[d=i*16+g*4+r][q]
    float m = -INFINITY, l = 0.f;    // l: per-lane partial sum (reduced in epilogue)

    const int nkt = 2 * qt + 2;            // block-level 64-key tiles
    const int myNkt = nkt - (w < 4 ? 1 : 0);  // lower waves: last tile fully masked

    __syncthreads();                 // prev q-tile readers done; no DMAs outstanding
    // stage k-tile 0 -> buf 0 (async DMA; 512 threads cover 64x64 in one pass)
    gload16(kbase + (size_t)srow * DK + schs * 8, (char*)kt[0] + sbase * 16);
    gload16(vbase + (size_t)srow * TT + schs * 8, (char*)vt[0] + sbase * 16);

    #pragma unroll 1
    for(int kti = 0; kti < nkt; kti++){
      const int cur = kti & 1;
      __syncthreads();               // drains vmcnt: buf[cur] ready; buf[cur^1] readers done

      // async-prefetch next tile straight into buf[cur^1] (drained at next barrier)
      if(kti + 1 < nkt){
        const int k0n = (kti + 1) * 64;
        gload16(kbase + (size_t)(k0n + srow) * DK + schs * 8, (char*)kt[cur ^ 1] + sbase * 16);
        gload16(vbase + (size_t)srow * TT + k0n + schs * 8, (char*)vt[cur ^ 1] + sbase * 16);
      }

      if(kti < myNkt){
        // S^T = K Q : s[i][r] = S[key = k0+i*16+g*4+r][q]
        f32x4 s[4];
        __builtin_amdgcn_s_setprio(1);
        #pragma unroll
        for(int i = 0; i < 4; i++){
          f32x4 c = {};
          #pragma unroll
          for(int ks = 0; ks < 2; ks++){
            int rb = i * 16 + ln;
            int cb = ks * 64 + g * 16;
            short8 kfr = *(const short8*)((const char*)kt[cur] + rb * 128 + (cb ^ ((rb & 7) << 4)));
            c = MFMA(kfr, qf[ks], c);
          }
          s[i] = c;
        }
        __builtin_amdgcn_s_setprio(0);

        if(kti == myNkt - 1){          // causal mask (this wave's diagonal tile)
          const int k0 = kti * 64;
          #pragma unroll
          for(int i = 0; i < 4; i++)
            #pragma unroll
            for(int r = 0; r < 4; r++)
              if(k0 + i * 16 + g * 4 + r > q) s[i][r] = -INFINITY;
        }

        // in-register row max (16 regs) + cross-group permlane swaps (full row = 4 groups)
        float mx0 = fmaxf(fmaxf(s[0][0], s[0][1]), fmaxf(s[0][2], s[0][3]));
        float mx1 = fmaxf(fmaxf(s[1][0], s[1][1]), fmaxf(s[1][2], s[1][3]));
        float mx2 = fmaxf(fmaxf(s[2][0], s[2][1]), fmaxf(s[2][2], s[2][3]));
        float mx3 = fmaxf(fmaxf(s[3][0], s[3][1]), fmaxf(s[3][2], s[3][3]));
        float pmax = fmaxf(fmaxf(mx0, mx1), fmaxf(mx2, mx3));
        pmax = plmax(pmax);

        // defer-max (T13): skip O-rescale when per-tile max growth <= 8 (exp2 domain)
        if(!__all(pmax <= m + 8.f)){
          float mnew = fmaxf(m, pmax);
          float alpha = EXP2(m - mnew);
          l *= alpha;
          #pragma unroll
          for(int i = 0; i < 4; i++)
            #pragma unroll
            for(int r = 0; r < 4; r++) o[i][r] *= alpha;
          m = mnew;
        }

        #pragma unroll
        for(int i = 0; i < 4; i++)
          #pragma unroll
          for(int r = 0; r < 4; r++){
            float p = EXP2(s[i][r] - m);
            s[i][r] = p; l += p;        // per-lane partial only
          }

        // pack P to bf16 B-frags in-register: pb[ks] reg j holds key kappa(g,j)+32ks
        union PU { short8 s8; unsigned w[4]; };
        PU pb[2];
        #pragma unroll
        for(int ks = 0; ks < 2; ks++){
          pb[ks].w[0] = cvtpk(s[2*ks][0],   s[2*ks][1]);
          pb[ks].w[1] = cvtpk(s[2*ks][2],   s[2*ks][3]);
          pb[ks].w[2] = cvtpk(s[2*ks+1][0], s[2*ks+1][1]);
          pb[ks].w[3] = cvtpk(s[2*ks+1][2], s[2*ks+1][3]);
        }

        // O^T += V^T P^T : key-permuted vt makes each A-frag ONE swizzled b128 read
        __builtin_amdgcn_s_setprio(1);
        #pragma unroll
        for(int i = 0; i < 4; i++){
          int dr = i * 16 + ln;
          const char* vrow = (const char*)vt[cur] + dr * 128;
          int sw = (dr & 7) << 4;
          #pragma unroll
          for(int ks = 0; ks < 2; ks++){
            short8 av = *(const short8*)(vrow + ((64 * ks + g * 16) ^ sw));
            o[i] = MFMA(av, pb[ks].s8, o[i]);
          }
        }
        __builtin_amdgcn_s_setprio(0);
      }
    }

    // epilogue: deferred l reduce, then out (B,T,DM) fp32, float4 stores
    l = plsum(l);
    float inv = 1.0f / l;
    float* orow = out + ((size_t)(b * TT + q)) * DM + h * 64 + g * 4;
    #pragma unroll
    for(int i = 0; i < 4; i++){
      float4 v4;
      v4.x = o[i][0] * inv; v4.y = o[i][1] * inv;
      v4.z = o[i][2] * inv; v4.w = o[i][3] * inv;
      *(float4*)(orow + i * 16) = v4;
    }
  }
}

extern "C" void kernel_launch(void* const* d_in, const int* in_sizes, int n_in,
                              void* d_out, int out_size, void* d_ws, size_t ws_size,
                              hipStream_t stream){
  const float* x  = (const float*)d_in[0];
  const float* Wq = (const float*)d_in[1];
  const float* bq = (const float*)d_in[2];
  const float* Wk = (const float*)d_in[3];
  const float* bk = (const float*)d_in[4];
  const float* Wv = (const float*)d_in[5];
  const float* bv = (const float*)d_in[6];
  float* out = (float*)d_out;

  char* ws = (char*)d_ws;
  u16* xb   = (u16*)(ws);                       // 16 MB  x bf16 (M,K)
  u16* wtq  = (u16*)(ws + (16u << 20));         //  2 MB  Wq^T bf16 (N,K)
  u16* wtk  = (u16*)(ws + (18u << 20));
  u16* wtv  = (u16*)(ws + (20u << 20));
  u16* qws  = (u16*)(ws + (22u << 20));         // 16 MB  Q (BH,T,DK) bf16 (pre-scaled)
  u16* kws  = (u16*)(ws + (38u << 20));         // 16 MB  K (BH,T,DK) bf16
  u16* vtws = (u16*)(ws + (54u << 20));         // 16 MB  V^T (BH,DK,T) bf16, key-permuted

  static bool qkv8_init = false;
  if(!qkv8_init){
    hipFuncSetAttribute((const void*)qkv8,
                        hipFuncAttributeMaxDynamicSharedMemorySize, 131072);
    qkv8_init = true;
  }

  cvt_x<<<dim3(BT * DM / 1024), dim3(256), 0, stream>>>(x, xb);
  twp<<<dim3(32, 32, 3), dim3(256), 0, stream>>>(Wq, Wk, Wv, wtq, wtk, wtv);
  qkv8<<<dim3(384), dim3(512), 131072, stream>>>(xb, wtq, wtk, wtv, bq, bk, bv, qws, kws, vtws);
  attn<<<dim3(512), dim3(512), 0, stream>>>(qws, kws, vtws, out);
}

// Round 8
// 153.340 us; speedup vs baseline: 1.0157x; 1.0157x over previous
//
#include <hip/hip_runtime.h>
#include <hip/hip_bf16.h>

#define DM 1024
#define NH 16
#define DK 64
#define TT 2048
#define NBATCH 4
#define BT 8192   // NBATCH*TT

typedef __attribute__((ext_vector_type(8))) short short8;
typedef __attribute__((ext_vector_type(4))) float f32x4;
typedef __attribute__((ext_vector_type(16))) float f32x16;
typedef unsigned short u16;

#define MFMA(a,b,c)   __builtin_amdgcn_mfma_f32_16x16x32_bf16((a),(b),(c),0,0,0)
#define MFMA32(a,b,c) __builtin_amdgcn_mfma_f32_32x32x16_bf16((a),(b),(c),0,0,0)

// 1/sqrt(64) * log2(e): folded into Q so attn softmax can use exp2 directly
#define QSCALE 0.18033688011112684f

// raw v_exp_f32 (flush-denorm fine for softmax), skips OCML fixup code
#define EXP2(x) __builtin_amdgcn_exp2f(x)

#define HAS_PLSWAP (__has_builtin(__builtin_amdgcn_permlane32_swap))

__device__ __forceinline__ u16 f2bf(float f){
  union { float f; unsigned u; } v; v.f = f;
  return (u16)((v.u + 0x7fffu + ((v.u >> 16) & 1u)) >> 16);
}

__device__ __forceinline__ unsigned cvtpk(float lo, float hi){
  unsigned r;
  asm("v_cvt_pk_bf16_f32 %0, %1, %2" : "=v"(r) : "v"(lo), "v"(hi));
  return r;
}

// async global->LDS DMA, 16B/lane. LDS dest must be wave-uniform base (+lane*16).
__device__ __forceinline__ void gload16(const void* g, void* l){
  __builtin_amdgcn_global_load_lds((__attribute__((address_space(1))) void*)(g),
                                   (__attribute__((address_space(3))) void*)(l), 16, 0, 0);
}

// lane ^32 reduces (lanes i and i^32 hold the same q-row's two key-halves)
__device__ __forceinline__ float plmax32(float x){
#if HAS_PLSWAP
  auto r = __builtin_amdgcn_permlane32_swap(__float_as_uint(x), __float_as_uint(x), false, false);
  return fmaxf(__uint_as_float(r[0]), __uint_as_float(r[1]));
#else
  return fmaxf(x, __shfl_xor(x, 32, 64));
#endif
}
__device__ __forceinline__ float plsum32(float x){
#if HAS_PLSWAP
  auto r = __builtin_amdgcn_permlane32_swap(__float_as_uint(x), __float_as_uint(x), false, false);
  return __uint_as_float(r[0]) + __uint_as_float(r[1]);
#else
  return x + __shfl_xor(x, 32, 64);
#endif
}

// T12 pack primitive: given per-lane A (own pair) and C (the +4-rowidx pair),
// returns w_lo = {A.lo32, C.lo32} and w_hi = {A.hi32, C.hi32} across the wave.
__device__ __forceinline__ void plpack(unsigned A, unsigned C, unsigned& wlo, unsigned& whi){
#if HAS_PLSWAP
  auto r = __builtin_amdgcn_permlane32_swap(A, C, false, false);
  wlo = r[0]; whi = r[1];
#else
  unsigned pa = __shfl_xor(A, 32, 64), pc = __shfl_xor(C, 32, 64);
  int hi = (threadIdx.x & 32) != 0;
  wlo = hi ? pc : A;
  whi = hi ? C : pa;
#endif
}

// ---------------- x fp32 -> bf16 ----------------
__global__ __launch_bounds__(256) void cvt_x(const float* __restrict__ x, u16* __restrict__ xb){
  int i = (blockIdx.x * 256 + threadIdx.x) * 4;
  float4 v = *(const float4*)(x + i);
  u16 o0 = f2bf(v.x), o1 = f2bf(v.y), o2 = f2bf(v.z), o3 = f2bf(v.w);
  ushort4 o; o.x=o0; o.y=o1; o.z=o2; o.w=o3;
  *(ushort4*)(xb + i) = o;
}

// ---------------- W (K,N) fp32 -> wt (N,K) bf16, all 3 mats in one launch ----------------
__global__ __launch_bounds__(256) void twp(
    const float* __restrict__ Wq, const float* __restrict__ Wk, const float* __restrict__ Wv,
    u16* __restrict__ wtq, u16* __restrict__ wtk, u16* __restrict__ wtv){
  const float* W = (blockIdx.z == 0) ? Wq : (blockIdx.z == 1) ? Wk : Wv;
  u16* wt = (blockIdx.z == 0) ? wtq : (blockIdx.z == 1) ? wtk : wtv;
  __shared__ float tile[32][33];
  int k0 = blockIdx.x * 32, n0 = blockIdx.y * 32;
  int tx = threadIdx.x & 31, ty = threadIdx.x >> 5;
  #pragma unroll
  for(int r = ty; r < 32; r += 8)
    tile[r][tx] = W[(size_t)(k0 + r) * DM + n0 + tx];
  __syncthreads();
  #pragma unroll
  for(int r = ty; r < 32; r += 8)
    wt[(size_t)(n0 + r) * DM + k0 + tx] = f2bf(tile[tx][r]);
}

// ---------------- QKV projection GEMM (R6-verified 2-phase dbuf, 72us) ----------------
// 128x128 tile, 4 waves; global_load_lds staging (linear dest, inverse-swizzled
// source); double-buffered: prefetch t+1 issued after the barrier, drained at the
// NEXT barrier. XCD-locality 1-D grid. V^T store now PLAIN (no key-permutation —
// the 32x32 attn consumes natural V^T layout).
__global__ __launch_bounds__(256) void qkv_gemm(
    const u16* __restrict__ xb,
    const u16* __restrict__ wtq, const u16* __restrict__ wtk, const u16* __restrict__ wtv,
    const float* __restrict__ bq, const float* __restrict__ bk, const float* __restrict__ bv,
    u16* __restrict__ qws, u16* __restrict__ kws, u16* __restrict__ vtws){
  __shared__ u16 sa[2][128 * 64];
  __shared__ u16 sb[2][128 * 64];
  const int id = blockIdx.x;              // 0..1535
  const int idx = id >> 3;                // 0..191 within XCD
  const int mt = (id & 7) * 8 + (idx & 7);// M-tile 0..63
  const int y  = idx >> 3;                // weight panel 0..23
  const int m0 = mt * 128;
  const int ng = y * 128;
  const int mat = ng >> 10;
  const int n0 = ng & 1023;
  const u16* wt = (mat == 0) ? wtq : (mat == 1) ? wtk : wtv;
  const float* bias = (mat == 0) ? bq : (mat == 1) ? bk : bv;
  const int tid = threadIdx.x;
  const int lane = tid & 63, w = tid >> 6;
  const int wm = (w >> 1) * 64, wn = (w & 1) * 64;
  const int wbase0 = tid & 192;   // w*64, wave-uniform

  f32x4 acc[4][4] = {};

  // stage K-tile 0 -> buf 0 (async DMA)
  #pragma unroll
  for(int p = 0; p < 4; p++){
    int base = p * 256 + wbase0;
    int idx2 = base + lane;
    int row = idx2 >> 3;
    int chs = (idx2 & 7) ^ (row & 7);
    gload16(xb + (size_t)(m0 + row) * 1024 + chs * 8, (char*)sa[0] + base * 16);
    gload16(wt + (size_t)(n0 + row) * 1024 + chs * 8, (char*)sb[0] + base * 16);
  }

  #pragma unroll 1
  for(int kt = 0; kt < 16; kt++){
    const int cur = kt & 1;
    __syncthreads();               // drains vmcnt: buf[cur] ready; buf[cur^1] readers done

    if(kt + 1 < 16){
      const int k0n = (kt + 1) * 64;
      #pragma unroll
      for(int p = 0; p < 4; p++){
        int base = p * 256 + wbase0;
        int idx2 = base + lane;
        int row = idx2 >> 3;
        int chs = (idx2 & 7) ^ (row & 7);
        gload16(xb + (size_t)(m0 + row) * 1024 + k0n + chs * 8, (char*)sa[cur ^ 1] + base * 16);
        gload16(wt + (size_t)(n0 + row) * 1024 + k0n + chs * 8, (char*)sb[cur ^ 1] + base * 16);
      }
    }

    #pragma unroll
    for(int ks = 0; ks < 2; ks++){
      short8 af[4], bfr[4];
      #pragma unroll
      for(int i = 0; i < 4; i++){
        int ra = wm + i * 16 + (lane & 15);
        int ca = ks * 64 + (lane >> 4) * 16;
        af[i] = *(const short8*)((const char*)sa[cur] + ra * 128 + (ca ^ ((ra & 7) << 4)));
        int rb = wn + i * 16 + (lane & 15);
        bfr[i] = *(const short8*)((const char*)sb[cur] + rb * 128 + (ca ^ ((rb & 7) << 4)));
      }
      __builtin_amdgcn_s_setprio(1);
      #pragma unroll
      for(int i = 0; i < 4; i++)
        #pragma unroll
        for(int j = 0; j < 4; j++)
          acc[i][j] = MFMA(af[i], bfr[j], acc[i][j]);
      __builtin_amdgcn_s_setprio(0);
    }
  }

  const float scl = (mat == 0) ? QSCALE : 1.0f;
  #pragma unroll
  for(int j = 0; j < 4; j++){
    int n = n0 + wn + j * 16 + (lane & 15);
    float bv_ = bias[n];
    int h = n >> 6, d = n & 63;
    #pragma unroll
    for(int i = 0; i < 4; i++){
      int mb = m0 + wm + i * 16 + (lane >> 4) * 4;
      int b = mb >> 11, t = mb & 2047;
      int bh = b * NH + h;
      if(mat == 2){
        // plain V^T (BH, d, t): r-quad = 4 consecutive t -> one 8B store
        ushort4 o4;
        o4.x = f2bf(acc[i][j][0] + bv_);
        o4.y = f2bf(acc[i][j][1] + bv_);
        o4.z = f2bf(acc[i][j][2] + bv_);
        o4.w = f2bf(acc[i][j][3] + bv_);
        *(ushort4*)(vtws + ((size_t)bh * DK + d) * TT + t) = o4;
      } else {
        u16* dst = (mat == 0) ? qws : kws;
        #pragma unroll
        for(int r = 0; r < 4; r++){
          u16 o = f2bf((acc[i][j][r] + bv_) * scl);
          dst[((size_t)bh * TT + t + r) * DK + d] = o;
        }
      }
    }
  }
}

// ---------------- flash attention, 32x32 MFMA core (halves LDS bytes/FLOP) ----------------
// R6 accounting proved attn LDS-BW-bound: 2 blocks x 8 waves x 16 b128 + 32KB DMA
// = 2048 cyc/CU-iter vs 2118 measured. 32x32x16 MFMA reads 1KB per 32K FLOP (vs
// 16K) -> wave owns 32 q-rows, 4-wave/256-thread blocks, LDS traffic per block-
// iter halves. Grid 512, XCD-bijective, pairs (x,15-x) -> exactly 34 iters/block.
// Layouts: C/D col=lane&31, row=(r&3)+8*(r>>2)+4*hi [m74/m101]; A/B k=hi*8+j.
// Softmax: 32 lane-local scores, one ^32 swap; P->bf16 via T12 (16 cvt_pk +
// 8 permlane32_swap: w_lo/w_hi = swap(cvtpk(own pair), cvtpk(+4-rowidx pair))).
// Waves 0,1 skip their fully-masked last tile; diagonal mask on own last tile.
__global__ __launch_bounds__(256) void attn(
    const u16* __restrict__ qws, const u16* __restrict__ kws, const u16* __restrict__ vtws,
    float* __restrict__ out){
  __shared__ u16 kt[2][64 * 64];    // [buf][key][d]  swizzled
  __shared__ u16 vt[2][64 * 64];    // [buf][d][key]  swizzled (plain V^T)

  const int id = blockIdx.x;
  const int swz = (id & 7) * 64 + (id >> 3);   // bijective (512 % 8 == 0)
  const int qx = swz & 7;                      // pair index 0..7
  const int bh = swz >> 3;

  const int tid = threadIdx.x, lane = tid & 63, w = tid >> 6;   // w 0..3
  const int hi = lane >> 5, lq = lane & 31;
  const int b = bh >> 4, h = bh & 15;
  const u16* kbase = kws + (size_t)bh * TT * DK;
  const u16* vbase = vtws + (size_t)bh * DK * TT;
  const int sw0 = (lq & 7) << 4;               // read swizzle (row&7 == lq&7 both chunks)

  #pragma unroll 1
  for(int qi = 0; qi < 2; qi++){
    const int qt = qi ? (15 - qx) : qx;        // 128-row q-tile 0..15
    const int q = qt * 128 + w * 32 + lq;      // this lane's q row

    // Q fragment (B-operand, pre-scaled): step s gives k-slots d = 16s + 8hi + j
    short8 qf[4];
    {
      const u16* gq = qws + ((size_t)bh * TT + q) * DK + hi * 8;
      #pragma unroll
      for(int s = 0; s < 4; s++) qf[s] = *(const short8*)(gq + s * 16);
    }

    f32x16 o0 = {}, o1 = {};         // O^T: d-chunk 0/1, d = c*32 + (r&3)+8*(r>>2)+4*hi
    float m = -INFINITY, l = 0.f;

    const int nkt = 2 * qt + 2;
    const int myNkt = 2 * qt + (w >> 1) + 1;   // waves 0,1 skip last (fully masked) tile

    __syncthreads();                 // prev q-tile readers done; no DMAs outstanding
    #pragma unroll
    for(int p = 0; p < 2; p++){      // stage k-tile 0 -> buf 0 (async DMA)
      int base = p * 256 + (tid & 192);
      int ci = base + lane, row = ci >> 3, chs = (ci & 7) ^ (row & 7);
      gload16(kbase + (size_t)row * DK + chs * 8, (char*)kt[0] + base * 16);
      gload16(vbase + (size_t)row * TT + chs * 8, (char*)vt[0] + base * 16);
    }

    #pragma unroll 1
    for(int kti = 0; kti < nkt; kti++){
      const int cur = kti & 1;
      __syncthreads();               // buf[cur] ready; buf[cur^1] readers done

      if(kti + 1 < nkt){             // prefetch next tile into buf[cur^1]
        const int k0n = (kti + 1) * 64;
        #pragma unroll
        for(int p = 0; p < 2; p++){
          int base = p * 256 + (tid & 192);
          int ci = base + lane, row = ci >> 3, chs = (ci & 7) ^ (row & 7);
          gload16(kbase + (size_t)(k0n + row) * DK + chs * 8, (char*)kt[cur ^ 1] + base * 16);
          gload16(vbase + (size_t)row * TT + k0n + chs * 8, (char*)vt[cur ^ 1] + base * 16);
        }
      }

      if(kti < myNkt){
        // S^T = K Q^T : chunk c keys c*32 + (r&3)+8*(r>>2)+4*hi, col q = lq
        f32x16 s0 = {}, s1 = {};
        __builtin_amdgcn_s_setprio(1);
        #pragma unroll
        for(int s = 0; s < 4; s++){
          int colb = 32 * s + 16 * hi;
          short8 k0f = *(const short8*)((const char*)kt[cur] + lq * 128 + (colb ^ sw0));
          short8 k1f = *(const short8*)((const char*)kt[cur] + (32 + lq) * 128 + (colb ^ sw0));
          s0 = MFMA32(k0f, qf[s], s0);
          s1 = MFMA32(k1f, qf[s], s1);
        }
        __builtin_amdgcn_s_setprio(0);

        if(kti == myNkt - 1){        // causal mask (this wave's diagonal tile)
          const int k0 = kti * 64;
          #pragma unroll
          for(int r = 0; r < 16; r++){
            int key = k0 + (r & 3) + 8 * (r >> 2) + 4 * hi;
            if(key > q)      s0[r] = -INFINITY;
            if(key + 32 > q) s1[r] = -INFINITY;
          }
        }

        // row max: 32 lane-local values -> tree -> one ^32 swap
        float px0, px1, px2, px3, px4, px5, px6, px7;
        px0 = fmaxf(fmaxf(s0[0], s0[1]),  fmaxf(s0[2], s0[3]));
        px1 = fmaxf(fmaxf(s0[4], s0[5]),  fmaxf(s0[6], s0[7]));
        px2 = fmaxf(fmaxf(s0[8], s0[9]),  fmaxf(s0[10], s0[11]));
        px3 = fmaxf(fmaxf(s0[12], s0[13]), fmaxf(s0[14], s0[15]));
        px4 = fmaxf(fmaxf(s1[0], s1[1]),  fmaxf(s1[2], s1[3]));
        px5 = fmaxf(fmaxf(s1[4], s1[5]),  fmaxf(s1[6], s1[7]));
        px6 = fmaxf(fmaxf(s1[8], s1[9]),  fmaxf(s1[10], s1[11]));
        px7 = fmaxf(fmaxf(s1[12], s1[13]), fmaxf(s1[14], s1[15]));
        float pmax = fmaxf(fmaxf(fmaxf(px0, px1), fmaxf(px2, px3)),
                           fmaxf(fmaxf(px4, px5), fmaxf(px6, px7)));
        pmax = plmax32(pmax);

        // defer-max (T13)
        if(!__all(pmax <= m + 8.f)){
          float mnew = fmaxf(m, pmax);
          float alpha = EXP2(m - mnew);
          l *= alpha;
          #pragma unroll
          for(int r = 0; r < 16; r++){ o0[r] *= alpha; o1[r] *= alpha; }
          m = mnew;
        }

        #pragma unroll
        for(int r = 0; r < 16; r++){
          float p0 = EXP2(s0[r] - m); s0[r] = p0;
          float p1 = EXP2(s1[r] - m); s1[r] = p1;
          l += p0 + p1;
        }

        // pack P -> bf16 B-frags: pb[s] slot j = key 16s + 8hi + j (T12 recipe)
        union PU { short8 s8; unsigned u[4]; };
        PU pb[4];
        #pragma unroll
        for(int s = 0; s < 4; s++){
          const int u_ = s & 1;                // 0: rowidx 0-15, 1: 16-31 (within chunk)
          unsigned A, B, C2, D2;
          if((s >> 1) == 0){
            A  = cvtpk(s0[8*u_ + 0], s0[8*u_ + 1]);
            B  = cvtpk(s0[8*u_ + 2], s0[8*u_ + 3]);
            C2 = cvtpk(s0[8*u_ + 4], s0[8*u_ + 5]);
            D2 = cvtpk(s0[8*u_ + 6], s0[8*u_ + 7]);
          } else {
            A  = cvtpk(s1[8*u_ + 0], s1[8*u_ + 1]);
            B  = cvtpk(s1[8*u_ + 2], s1[8*u_ + 3]);
            C2 = cvtpk(s1[8*u_ + 4], s1[8*u_ + 5]);
            D2 = cvtpk(s1[8*u_ + 6], s1[8*u_ + 7]);
          }
          plpack(A, C2, pb[s].u[0], pb[s].u[2]);
          plpack(B, D2, pb[s].u[1], pb[s].u[3]);
        }

        // O^T += V^T P^T : A-frag = V^T[d][key] rows d = c*32+lq, 16B per step
        __builtin_amdgcn_s_setprio(1);
        #pragma unroll
        for(int s = 0; s < 4; s++){
          int colb = 32 * s + 16 * hi;
          short8 v0 = *(const short8*)((const char*)vt[cur] + lq * 128 + (colb ^ sw0));
          short8 v1 = *(const short8*)((const char*)vt[cur] + (32 + lq) * 128 + (colb ^ sw0));
          o0 = MFMA32(v0, pb[s].s8, o0);
          o1 = MFMA32(v1, pb[s].s8, o1);
        }
        __builtin_amdgcn_s_setprio(0);
      }
    }

    // epilogue: l reduce (^32), then 8 float4 stores; d = c*32 + 8*rq + 4*hi + t
    l = plsum32(l);
    float inv = 1.0f / l;
    float* orow = out + ((size_t)(b * TT + q)) * DM + h * 64;
    #pragma unroll
    for(int rq = 0; rq < 4; rq++){
      float4 v4;
      v4.x = o0[4*rq + 0] * inv; v4.y = o0[4*rq + 1] * inv;
      v4.z = o0[4*rq + 2] * inv; v4.w = o0[4*rq + 3] * inv;
      *(float4*)(orow + rq * 8 + hi * 4) = v4;
      float4 v5;
      v5.x = o1[4*rq + 0] * inv; v5.y = o1[4*rq + 1] * inv;
      v5.z = o1[4*rq + 2] * inv; v5.w = o1[4*rq + 3] * inv;
      *(float4*)(orow + 32 + rq * 8 + hi * 4) = v5;
    }
  }
}

extern "C" void kernel_launch(void* const* d_in, const int* in_sizes, int n_in,
                              void* d_out, int out_size, void* d_ws, size_t ws_size,
                              hipStream_t stream){
  const float* x  = (const float*)d_in[0];
  const float* Wq = (const float*)d_in[1];
  const float* bq = (const float*)d_in[2];
  const float* Wk = (const float*)d_in[3];
  const float* bk = (const float*)d_in[4];
  const float* Wv = (const float*)d_in[5];
  const float* bv = (const float*)d_in[6];
  float* out = (float*)d_out;

  char* ws = (char*)d_ws;
  u16* xb   = (u16*)(ws);                       // 16 MB  x bf16 (M,K)
  u16* wtq  = (u16*)(ws + (16u << 20));         //  2 MB  Wq^T bf16 (N,K)
  u16* wtk  = (u16*)(ws + (18u << 20));
  u16* wtv  = (u16*)(ws + (20u << 20));
  u16* qws  = (u16*)(ws + (22u << 20));         // 16 MB  Q (BH,T,DK) bf16 (pre-scaled)
  u16* kws  = (u16*)(ws + (38u << 20));         // 16 MB  K (BH,T,DK) bf16
  u16* vtws = (u16*)(ws + (54u << 20));         // 16 MB  V^T (BH,DK,T) bf16, plain

  cvt_x<<<dim3(BT * DM / 1024), dim3(256), 0, stream>>>(x, xb);
  twp<<<dim3(32, 32, 3), dim3(256), 0, stream>>>(Wq, Wk, Wv, wtq, wtk, wtv);
  qkv_gemm<<<dim3(1536), dim3(256), 0, stream>>>(xb, wtq, wtk, wtv, bq, bk, bv, qws, kws, vtws);
  attn<<<dim3(512), dim3(256), 0, stream>>>(qws, kws, vtws, out);
}